// Round 14
// baseline (139.666 us; speedup 1.0000x reference)
//
#include <hip/hip_runtime.h>
#include <hip/hip_bf16.h>

#define N_SAMPLES 262144
#define NUM_FLOWS 8
#define BLOCK 256
#define WAVES 4
#define MT 2                                    // 16-sample col-tiles per wave
#define SAMPLES_PER_BLOCK (WAVES * MT * 16)     // 128
#define NBLOCKS (N_SAMPLES / SAMPLES_PER_BLOCK) // 2048

// d_ws float layout:
#define OFF_B2    0        // 512 f32
#define OFF_W1B   512      // 512 bf16 (256 floats)
#define OFF_B1B   768      // 512 bf16 (256 floats)
#define SP_FLOATS 1024     // ^^^ this prefix is staged to LDS
#define OFF_B3    1024     // 32
#define OFF_CONST 1056     // 8 x 16: wm[9], els[3], sh[3], pad
#define OFF_LC    1184     // 12
#define OFF_MEAN  1196     // 3
#define OFF_LDB   1199     // 1
#define OFF_A3    1200     // W3 A-frags (quad-replicated) bf16: 8*2*64*8 = 8192 bf16
#define WS_PARAMS 5296     // floats
#define WS_W2_BYTE_OFF (WS_PARAMS * 4)  // 21184 (16B aligned)

typedef __attribute__((ext_vector_type(8))) short bf16x8;
typedef __attribute__((ext_vector_type(4))) short shortx4;
typedef __attribute__((ext_vector_type(4))) float floatx4;

union FragU { bf16x8 v; __hip_bfloat162 p[4]; __hip_bfloat16 e[8]; };
union S4U   { shortx4 v; __hip_bfloat16 e[4]; };

__device__ __forceinline__ float b2f(__hip_bfloat16 x) { return __bfloat162float(x); }

// dtype-flexible load/store; f32 flag is grid-uniform (sniffed from L_tril[0][1]==0).
__device__ __forceinline__ float ldv(const void* p, int i, bool f32) {
    return f32 ? ((const float*)p)[i] : b2f(((const __hip_bfloat16*)p)[i]);
}
__device__ __forceinline__ void stv(void* p, int i, float v, bool f32) {
    if (f32) ((float*)p)[i] = v;
    else ((__hip_bfloat16*)p)[i] = __float2bfloat16(v);
}

// ---------------- prep kernel: runs once per launch, 9 blocks ----------------
__global__ void prep_kernel(
    const void* __restrict__ g_L_tril,
    const void* __restrict__ g_base_mean,
    const void* __restrict__ g_an_log_scale,
    const void* __restrict__ g_an_shift,
    const void* __restrict__ g_perm_p,
    const void* __restrict__ g_sign_s,
    const void* __restrict__ g_lu_l,
    const void* __restrict__ g_lu_u,
    const void* __restrict__ g_lu_log_s,
    const void* __restrict__ g_W1,
    const void* __restrict__ g_b1,
    const void* __restrict__ g_W2,
    const void* __restrict__ g_b2,
    const void* __restrict__ g_W3,
    const void* __restrict__ g_b3,
    float* __restrict__ ws)
{
    const bool f32 = (((const float*)g_L_tril)[1] == 0.0f);
    const int f = blockIdx.x;
    const int tid = threadIdx.x;
    __hip_bfloat16* wsW2  = (__hip_bfloat16*)((char*)ws + WS_W2_BYTE_OFF);
    __hip_bfloat16* wsA3  = (__hip_bfloat16*)(ws + OFF_A3);
    __hip_bfloat16* wsW1b = (__hip_bfloat16*)(ws + OFF_W1B);
    __hip_bfloat16* wsB1b = (__hip_bfloat16*)(ws + OFF_B1B);

    if (f < NUM_FLOWS) {
        // W2 -> bf16 MFMA-A-frag order. flow-local elem (n,k) ->
        // frag (kc=k>>5, jt=n>>4), lane ((k>>3)&3)*16 + (n&15), slot k&7
        for (int i4 = tid; i4 < 1024; i4 += BLOCK) {
            int e = i4 << 2;
            int n = e >> 6, k = e & 63;
            int dst = ((k >> 5) * 4 + (n >> 4)) * 512 + (((k >> 3) & 3) * 16 + (n & 15)) * 8 + (k & 7);
            S4U u;
            if (f32) {
                float4 v = ((const float4*)g_W2)[f * 1024 + i4];
                u.e[0] = __float2bfloat16(v.x);
                u.e[1] = __float2bfloat16(v.y);
                u.e[2] = __float2bfloat16(v.z);
                u.e[3] = __float2bfloat16(v.w);
            } else {
                u.v = ((const shortx4*)g_W2)[f * 1024 + i4];
            }
            *(shortx4*)&wsW2[f * 4096 + dst] = u.v;
        }
        // W3 -> bf16 A-fragment, neuron-relabeled AND quad-replicated:
        // A3[m][k3] = W3[m & 3][n(k3)] so C3[m=quad*4+r][col] = out[r][col] for
        // every quad — no cross-lane broadcast needed.
        if (tid < 128) {
            int kc2 = tid >> 6, L = tid & 63;
            int m = L & 15, qd = L >> 4;
            FragU fr;
#pragma unroll
            for (int j = 0; j < 8; ++j) {
                int jt = ((j >> 2) << 1) | kc2;
                int r  = j & 3;
                int n  = jt * 16 + qd * 4 + r;
                fr.e[j] = __float2bfloat16(ldv(g_W3, f * 256 + (m & 3) * 64 + n, f32));
            }
            *(bf16x8*)&wsA3[(f * 2 + kc2) * 512 + L * 8] = fr.v;
        }
        if (tid < 64) {
            wsW1b[f * 64 + tid] = __float2bfloat16(ldv(g_W1, f * 64 + tid, f32));
            wsB1b[f * 64 + tid] = __float2bfloat16(ldv(g_b1, f * 64 + tid, f32));
            ws[OFF_B2 + f * 64 + tid] = ldv(g_b2, f * 64 + tid, f32);
        }
        if (tid < 4) ws[OFF_B3 + f * 4 + tid] = ldv(g_b3, f * 4 + tid, f32);
        if (tid == 0) {
            for (int d = 0; d < 3; ++d) {
                float ls = ldv(g_an_log_scale, f * 3 + d, f32);
                ws[OFF_CONST + f * 16 + 9 + d]  = __expf(ls);
                ws[OFF_CONST + f * 16 + 12 + d] = ldv(g_an_shift, f * 3 + d, f32);
            }
            float U[3][3], Lm[3][3], M[3][3], P[3][3];
            for (int i = 0; i < 3; ++i)
                for (int j = 0; j < 3; ++j) {
                    U[i][j]  = (j > i) ? ldv(g_lu_u, f * 9 + i * 3 + j, f32) : 0.f;
                    Lm[i][j] = (j < i) ? ldv(g_lu_l, f * 9 + i * 3 + j, f32) : (i == j ? 1.f : 0.f);
                    P[i][j]  = ldv(g_perm_p, f * 9 + i * 3 + j, f32);
                }
            for (int i = 0; i < 3; ++i)
                U[i][i] = ldv(g_sign_s, f * 3 + i, f32) * __expf(ldv(g_lu_log_s, f * 3 + i, f32));
            for (int i = 0; i < 3; ++i)
                for (int j = 0; j < 3; ++j) {
                    float s = 0.f;
                    for (int k = 0; k < 3; ++k) s += Lm[i][k] * U[k][j];
                    M[i][j] = s;
                }
            for (int i = 0; i < 3; ++i)
                for (int j = 0; j < 3; ++j) {
                    float s = 0.f;
                    for (int k = 0; k < 3; ++k) s += P[i][k] * M[k][j];
                    ws[OFF_CONST + f * 16 + i * 3 + j] = s;
                }
            ws[OFF_CONST + f * 16 + 15] = 0.f;
        }
    } else if (tid == 0) {
        // cholesky of cov = Lt Lt^T, mean, ldBase
        float Lt[3][3];
        for (int i = 0; i < 3; ++i)
            for (int j = 0; j < 3; ++j)
                Lt[i][j] = (j <= i) ? ldv(g_L_tril, i * 3 + j, f32) : 0.f;
        for (int i = 0; i < 3; ++i) Lt[i][i] += 1e-6f;
        float cov[3][3];
        for (int i = 0; i < 3; ++i)
            for (int j = 0; j < 3; ++j) {
                float s = 0.f;
                for (int k = 0; k < 3; ++k) s += Lt[i][k] * Lt[j][k];
                cov[i][j] = s;
            }
        float c00 = sqrtf(cov[0][0]);
        float c10 = cov[1][0] / c00, c20 = cov[2][0] / c00;
        float c11 = sqrtf(cov[1][1] - c10 * c10);
        float c21 = (cov[2][1] - c20 * c10) / c11;
        float c22 = sqrtf(cov[2][2] - c20 * c20 - c21 * c21);
        ws[OFF_LC + 0] = c00; ws[OFF_LC + 3] = c10; ws[OFF_LC + 4] = c11;
        ws[OFF_LC + 6] = c20; ws[OFF_LC + 7] = c21; ws[OFF_LC + 8] = c22;
        ws[OFF_LC + 1] = 0.f; ws[OFF_LC + 2] = 0.f; ws[OFF_LC + 5] = 0.f;
        ws[OFF_LC + 9] = 0.f; ws[OFF_LC + 10] = 0.f; ws[OFF_LC + 11] = 0.f;
        for (int d = 0; d < 3; ++d) ws[OFF_MEAN + d] = ldv(g_base_mean, d, f32);
        float ldb = 0.f;
        for (int i = 0; i < NUM_FLOWS * 3; ++i)
            ldb += ldv(g_an_log_scale, i, f32) + ldv(g_lu_log_s, i, f32);
        ws[OFF_LDB] = ldb;
    }
}

// per-flow global weight bundle (prefetched one flow ahead)
struct Frags {
    bf16x8 Af[2][4];
    bf16x8 A3f[2];
};

// ---------------- main kernel ----------------
// r13 structure + packed-bf16 layer-1 + software-pipelined weight loads
// (one-flow-ahead prefetch) + b3 folded into layer-3 MFMA C-init.
// launch_bounds (256,2): the only spill-free setting (r4/r7/r9/r12/r13);
// (256,3)/(256,4) triggered 86-144 MB scratch (r5/r6).
__global__ __launch_bounds__(BLOCK, 2) void glow_kernel(
    const void* __restrict__ g_eps,
    const void* __restrict__ g_L_tril,
    const float* __restrict__ ws,
    void* __restrict__ g_out)
{
    const bool f32 = (((const float*)g_L_tril)[1] == 0.0f);

    // stage only W1b/B1b/B2 (4 KB) in LDS; ONE barrier.
    __shared__ __align__(16) float sP[SP_FLOATS];
    for (int i = threadIdx.x; i < SP_FLOATS / 4; i += BLOCK)
        ((float4*)sP)[i] = ((const float4*)ws)[i];
    __syncthreads();

    const __hip_bfloat16* wsW2  = (const __hip_bfloat16*)((const char*)ws + WS_W2_BYTE_OFF);
    const __hip_bfloat16* wsA3  = (const __hip_bfloat16*)(ws + OFF_A3);
    const __hip_bfloat16* sW1b  = (const __hip_bfloat16*)(sP + OFF_W1B);
    const __hip_bfloat16* sB1b  = (const __hip_bfloat16*)(sP + OFF_B1B);

    const int tid  = threadIdx.x;
    const int lane = tid & 63;
    const int wave = tid >> 6;
    const int quad = lane >> 4;
    const int col  = lane & 15;
    const int base = blockIdx.x * SAMPLES_PER_BLOCK + wave * (MT * 16);

    // z init (col layout: sample = base + mt*16 + col, replicated over quads)
    float zc0[MT], zc1[MT], zc2[MT], lda[MT];
    {
        const float l00 = ws[OFF_LC + 0], l10 = ws[OFF_LC + 3], l11 = ws[OFF_LC + 4];
        const float l20 = ws[OFF_LC + 6], l21 = ws[OFF_LC + 7], l22 = ws[OFF_LC + 8];
        const float m0 = ws[OFF_MEAN], m1 = ws[OFF_MEAN + 1], m2 = ws[OFF_MEAN + 2];
#pragma unroll
        for (int mt = 0; mt < MT; ++mt) {
            int g = base + mt * 16 + col;
            float e0 = ldv(g_eps, g * 3 + 0, f32);
            float e1 = ldv(g_eps, g * 3 + 1, f32);
            float e2 = ldv(g_eps, g * 3 + 2, f32);
            zc0[mt] = m0 + l00 * e0;
            zc1[mt] = m1 + l10 * e0 + l11 * e1;
            zc2[mt] = m2 + l20 * e0 + l21 * e1 + l22 * e2;
            lda[mt] = 0.f;
        }
    }

    __hip_bfloat162 zero2;
    zero2.x = __float2bfloat16(0.f); zero2.y = zero2.x;

    auto loadFrags = [&](int f) {
        Frags fr;
#pragma unroll
        for (int kc = 0; kc < 2; ++kc)
#pragma unroll
            for (int jt = 0; jt < 4; ++jt)
                fr.Af[kc][jt] = *(const bf16x8*)&wsW2[f * 4096 + ((kc * 4 + jt) * 64 + lane) * 8];
#pragma unroll
        for (int kc2 = 0; kc2 < 2; ++kc2)
            fr.A3f[kc2] = *(const bf16x8*)&wsA3[((f * 2 + kc2) * 64 + lane) * 8];
        return fr;
    };

    auto flowBody = [&](int f, const Frags& fr) {
        // b2 rows from LDS (consumed as layer-2 C-init)
        floatx4 b2q[4];
#pragma unroll
        for (int jt = 0; jt < 4; ++jt)
            b2q[jt] = *(const floatx4*)&sP[OFF_B2 + f * 64 + jt * 16 + quad * 4];

        // wave-uniform tables from global (scalar loads, off LDS pipe)
        const floatx4* cp = (const floatx4*)&ws[OFF_CONST + f * 16];
        floatx4 c0 = cp[0], c1 = cp[1], c2 = cp[2], c3 = cp[3];
        floatx4 b3v = *(const floatx4*)&ws[OFF_B3 + f * 4];

        // actnorm + 1x1 affine (fp32)
#pragma unroll
        for (int mt = 0; mt < MT; ++mt) {
            float t0 = c2[1] * (zc0[mt] + c3[0]);
            float t1 = c2[2] * (zc1[mt] + c3[1]);
            float t2 = c2[3] * (zc2[mt] + c3[2]);
            zc0[mt] = c0[0] * t0 + c0[1] * t1 + c0[2] * t2;
            zc1[mt] = c0[3] * t0 + c1[0] * t1 + c1[1] * t2;
            zc2[mt] = c1[2] * t0 + c1[3] * t1 + c2[0] * t2;
        }

        // layer 1 (packed bf16): hB.p[i] = max(z0*w1 + b1, 0) two-at-a-time
        FragU hB[MT][2];
        __hip_bfloat162 z02[MT];
#pragma unroll
        for (int mt = 0; mt < MT; ++mt) {
            __hip_bfloat16 zb = __float2bfloat16(zc0[mt]);
            z02[mt].x = zb; z02[mt].y = zb;
        }
#pragma unroll
        for (int kc = 0; kc < 2; ++kc) {
            FragU w1u, b1u;
            w1u.v = *(const bf16x8*)&sW1b[f * 64 + kc * 32 + quad * 8];
            b1u.v = *(const bf16x8*)&sB1b[f * 64 + kc * 32 + quad * 8];
#pragma unroll
            for (int mt = 0; mt < MT; ++mt)
#pragma unroll
                for (int i = 0; i < 4; ++i)
                    hB[mt][kc].p[i] = __hmax2(__hfma2(z02[mt], w1u.p[i], b1u.p[i]), zero2);
        }

        // layer 2 (MFMA, b2 C-init) -> repack -> layer 3 (MFMA, b3 C-init)
#pragma unroll
        for (int mt = 0; mt < MT; ++mt) {
            floatx4 a2[4];
#pragma unroll
            for (int jt = 0; jt < 4; ++jt) {
                floatx4 acc = __builtin_amdgcn_mfma_f32_16x16x32_bf16(fr.Af[0][jt], hB[mt][0].v, b2q[jt], 0, 0, 0);
                a2[jt] = __builtin_amdgcn_mfma_f32_16x16x32_bf16(fr.Af[1][jt], hB[mt][1].v, acc, 0, 0, 0);
            }
            // relu + pack: C pos (jt,r) -> B3 frag kc2 = jt&1, elem (jt>>1)*4 + r
            FragU h3[2];
#pragma unroll
            for (int jt = 0; jt < 4; ++jt) {
                int kc2 = jt & 1, pb = (jt >> 1) * 2;
                h3[kc2].p[pb]     = __float22bfloat162_rn(make_float2(fmaxf(a2[jt][0], 0.f), fmaxf(a2[jt][1], 0.f)));
                h3[kc2].p[pb + 1] = __float22bfloat162_rn(make_float2(fmaxf(a2[jt][2], 0.f), fmaxf(a2[jt][3], 0.f)));
            }
            floatx4 acc3 = b3v;  // b3 folded into C-init (quad-replicated A3)
            acc3 = __builtin_amdgcn_mfma_f32_16x16x32_bf16(fr.A3f[0], h3[0].v, acc3, 0, 0, 0);
            acc3 = __builtin_amdgcn_mfma_f32_16x16x32_bf16(fr.A3f[1], h3[1].v, acc3, 0, 0, 0);
            float ls0 = acc3[2], ls1 = acc3[3];
            zc1[mt] = fmaf(zc1[mt], __expf(ls0), acc3[0]);
            zc2[mt] = fmaf(zc2[mt], __expf(ls1), acc3[1]);
            lda[mt] += ls0 + ls1;
        }
    };

    // software pipeline: prefetch weights one flow ahead
    Frags A = loadFrags(0);
#pragma unroll 1
    for (int fb = 0; fb < NUM_FLOWS; fb += 2) {
        Frags B = loadFrags(fb + 1);
        flowBody(fb, A);
        A = loadFrags(fb + 2 < NUM_FLOWS ? fb + 2 : NUM_FLOWS - 1);
        flowBody(fb + 1, B);
    }

    if (quad == 0) {
        const float ldBase = ws[OFF_LDB];
#pragma unroll
        for (int mt = 0; mt < MT; ++mt) {
            int g = base + mt * 16 + col;
            float z1 = zc1[mt], z2 = zc2[mt];
            stv(g_out, g * 3 + 0, zc0[mt], f32);
            stv(g_out, g * 3 + 1, __expf(z1), f32);
            stv(g_out, g * 3 + 2, __expf(z2), f32);
            stv(g_out, 3 * N_SAMPLES + g, lda[mt] + ldBase + z1 + z2, f32);
        }
    }
}

extern "C" void kernel_launch(void* const* d_in, const int* in_sizes, int n_in,
                              void* d_out, int out_size, void* d_ws, size_t ws_size,
                              hipStream_t stream) {
    prep_kernel<<<dim3(NUM_FLOWS + 1), dim3(BLOCK), 0, stream>>>(
        d_in[1], d_in[2], d_in[3], d_in[4], d_in[5], d_in[6], d_in[7],
        d_in[8], d_in[9], d_in[10], d_in[11], d_in[12], d_in[13], d_in[14], d_in[15],
        (float*)d_ws);
    glow_kernel<<<dim3(NBLOCKS), dim3(BLOCK), 0, stream>>>(
        d_in[0], d_in[1], (const float*)d_ws, d_out);
}

// Round 15
// 106.085 us; speedup vs baseline: 1.3165x; 1.3165x over previous
//
#include <hip/hip_runtime.h>
#include <hip/hip_bf16.h>

#define N_SAMPLES 262144
#define NUM_FLOWS 8
#define BLOCK 256
#define SPT 2                                   // samples per thread
#define NBLOCKS (N_SAMPLES / (BLOCK * SPT))     // 512

// piecewise-linear MLP table: out(z0) = (sh0, sh1, ls0, ls1), b3 folded in.
// MLP of relu/affine layers with scalar input is EXACTLY piecewise-linear;
// lerp error only in hinge cells, ~1e-5 (slope-change ~1e-3 x cell 0.023 / 4).
#define TABN 1024
#define TAB_LO (-12.0f)
#define TAB_HI (12.0f)
#define TAB_SCALE ((float)(TABN - 1) / (TAB_HI - TAB_LO))
#define TAB_STEP ((TAB_HI - TAB_LO) / (float)(TABN - 1))

// d_ws float layout
#define OFF_CONST 0     // 8 x 16: wm[9], els[3], sh[3], pad
#define OFF_LC    128   // 12
#define OFF_MEAN  140   // 3
#define OFF_LDB   143   // 1
#define OFF_TAB   144   // 8 x TABN x float4 = 32768 floats (128 KB)

typedef __attribute__((ext_vector_type(4))) float floatx4;

__device__ __forceinline__ float b2f(__hip_bfloat16 x) { return __bfloat162float(x); }

// dtype-flexible load/store; f32 flag is grid-uniform (sniffed from L_tril[0][1]==0).
__device__ __forceinline__ float ldv(const void* p, int i, bool f32) {
    return f32 ? ((const float*)p)[i] : b2f(((const __hip_bfloat16*)p)[i]);
}
__device__ __forceinline__ void stv(void* p, int i, float v, bool f32) {
    if (f32) ((float*)p)[i] = v;
    else ((__hip_bfloat16*)p)[i] = __float2bfloat16(v);
}

// ---------------- prep kernel: 129 blocks ----------------
// Blocks 0..127: build the per-flow PWL tables (16 chunks x 64 entries, 4
// threads per entry). Block 128: small precompute (wm, Lc, mean, ldb).
__global__ void prep_kernel(
    const void* __restrict__ g_L_tril,
    const void* __restrict__ g_base_mean,
    const void* __restrict__ g_an_log_scale,
    const void* __restrict__ g_an_shift,
    const void* __restrict__ g_perm_p,
    const void* __restrict__ g_sign_s,
    const void* __restrict__ g_lu_l,
    const void* __restrict__ g_lu_u,
    const void* __restrict__ g_lu_log_s,
    const void* __restrict__ g_W1,
    const void* __restrict__ g_b1,
    const void* __restrict__ g_W2,
    const void* __restrict__ g_b2,
    const void* __restrict__ g_W3,
    const void* __restrict__ g_b3,
    float* __restrict__ ws)
{
    const bool f32 = (((const float*)g_L_tril)[1] == 0.0f);
    const int bid = blockIdx.x;
    const int tid = threadIdx.x;

    if (bid < 128) {
        const int f = bid >> 4;
        const int chunk = bid & 15;
        __shared__ __align__(16) float sW2[4096];
        __shared__ __align__(16) float sW1[64], sB1[64], sB2[64];
        __shared__ __align__(16) float sW3[256];
        __shared__ float sB3[4];
        for (int i = tid; i < 4096; i += BLOCK) sW2[i] = ldv(g_W2, f * 4096 + i, f32);
        sW3[tid] = ldv(g_W3, f * 256 + tid, f32);
        if (tid < 64) {
            sW1[tid] = ldv(g_W1, f * 64 + tid, f32);
            sB1[tid] = ldv(g_b1, f * 64 + tid, f32);
            sB2[tid] = ldv(g_b2, f * 64 + tid, f32);
        }
        if (tid < 4) sB3[tid] = ldv(g_b3, f * 4 + tid, f32);
        __syncthreads();

        const int e = chunk * 64 + (tid >> 2);   // table entry
        const int q = tid & 3;                   // this thread's 16 rows
        const float z0 = TAB_LO + (float)e * TAB_STEP;

        float h1[64];
        const floatx4* w1v = (const floatx4*)sW1;
        const floatx4* b1v = (const floatx4*)sB1;
#pragma unroll
        for (int k4 = 0; k4 < 16; ++k4) {
            floatx4 w = w1v[k4], b = b1v[k4];
#pragma unroll
            for (int c = 0; c < 4; ++c)
                h1[k4 * 4 + c] = fmaxf(fmaf(z0, w[c], b[c]), 0.f);
        }
        float o0 = 0.f, o1 = 0.f, o2 = 0.f, o3 = 0.f;
        for (int jj = 0; jj < 16; ++jj) {
            int j = q * 16 + jj;
            const floatx4* row = (const floatx4*)&sW2[j * 64];
            float acc = sB2[j];
#pragma unroll
            for (int k4 = 0; k4 < 16; ++k4) {
                floatx4 w = row[k4];
                acc = fmaf(w[0], h1[k4 * 4 + 0], acc);
                acc = fmaf(w[1], h1[k4 * 4 + 1], acc);
                acc = fmaf(w[2], h1[k4 * 4 + 2], acc);
                acc = fmaf(w[3], h1[k4 * 4 + 3], acc);
            }
            float h2 = fmaxf(acc, 0.f);
            o0 = fmaf(sW3[0 * 64 + j], h2, o0);
            o1 = fmaf(sW3[1 * 64 + j], h2, o1);
            o2 = fmaf(sW3[2 * 64 + j], h2, o2);
            o3 = fmaf(sW3[3 * 64 + j], h2, o3);
        }
        // combine the 4 threads of this entry (lanes e*4+q, adjacent)
        o0 += __shfl_xor(o0, 1); o0 += __shfl_xor(o0, 2);
        o1 += __shfl_xor(o1, 1); o1 += __shfl_xor(o1, 2);
        o2 += __shfl_xor(o2, 1); o2 += __shfl_xor(o2, 2);
        o3 += __shfl_xor(o3, 1); o3 += __shfl_xor(o3, 2);
        if (q == 0) {
            floatx4 r = {o0 + sB3[0], o1 + sB3[1], o2 + sB3[2], o3 + sB3[3]};
            ((floatx4*)(ws + OFF_TAB))[f * TABN + e] = r;
        }
        return;
    }

    // ---- misc precompute block ----
    if (tid < NUM_FLOWS) {
        const int f = tid;
        for (int d = 0; d < 3; ++d) {
            float ls = ldv(g_an_log_scale, f * 3 + d, f32);
            ws[OFF_CONST + f * 16 + 9 + d]  = __expf(ls);
            ws[OFF_CONST + f * 16 + 12 + d] = ldv(g_an_shift, f * 3 + d, f32);
        }
        float U[3][3], Lm[3][3], M[3][3], P[3][3];
        for (int i = 0; i < 3; ++i)
            for (int j = 0; j < 3; ++j) {
                U[i][j]  = (j > i) ? ldv(g_lu_u, f * 9 + i * 3 + j, f32) : 0.f;
                Lm[i][j] = (j < i) ? ldv(g_lu_l, f * 9 + i * 3 + j, f32) : (i == j ? 1.f : 0.f);
                P[i][j]  = ldv(g_perm_p, f * 9 + i * 3 + j, f32);
            }
        for (int i = 0; i < 3; ++i)
            U[i][i] = ldv(g_sign_s, f * 3 + i, f32) * __expf(ldv(g_lu_log_s, f * 3 + i, f32));
        for (int i = 0; i < 3; ++i)
            for (int j = 0; j < 3; ++j) {
                float s = 0.f;
                for (int k = 0; k < 3; ++k) s += Lm[i][k] * U[k][j];
                M[i][j] = s;
            }
        for (int i = 0; i < 3; ++i)
            for (int j = 0; j < 3; ++j) {
                float s = 0.f;
                for (int k = 0; k < 3; ++k) s += P[i][k] * M[k][j];
                ws[OFF_CONST + f * 16 + i * 3 + j] = s;
            }
        ws[OFF_CONST + f * 16 + 15] = 0.f;
    } else if (tid == 8) {
        float Lt[3][3];
        for (int i = 0; i < 3; ++i)
            for (int j = 0; j < 3; ++j)
                Lt[i][j] = (j <= i) ? ldv(g_L_tril, i * 3 + j, f32) : 0.f;
        for (int i = 0; i < 3; ++i) Lt[i][i] += 1e-6f;
        float cov[3][3];
        for (int i = 0; i < 3; ++i)
            for (int j = 0; j < 3; ++j) {
                float s = 0.f;
                for (int k = 0; k < 3; ++k) s += Lt[i][k] * Lt[j][k];
                cov[i][j] = s;
            }
        float c00 = sqrtf(cov[0][0]);
        float c10 = cov[1][0] / c00, c20 = cov[2][0] / c00;
        float c11 = sqrtf(cov[1][1] - c10 * c10);
        float c21 = (cov[2][1] - c20 * c10) / c11;
        float c22 = sqrtf(cov[2][2] - c20 * c20 - c21 * c21);
        ws[OFF_LC + 0] = c00; ws[OFF_LC + 3] = c10; ws[OFF_LC + 4] = c11;
        ws[OFF_LC + 6] = c20; ws[OFF_LC + 7] = c21; ws[OFF_LC + 8] = c22;
        ws[OFF_LC + 1] = 0.f; ws[OFF_LC + 2] = 0.f; ws[OFF_LC + 5] = 0.f;
        ws[OFF_LC + 9] = 0.f; ws[OFF_LC + 10] = 0.f; ws[OFF_LC + 11] = 0.f;
        for (int d = 0; d < 3; ++d) ws[OFF_MEAN + d] = ldv(g_base_mean, d, f32);
        float ldb = 0.f;
        for (int i = 0; i < NUM_FLOWS * 3; ++i)
            ldb += ldv(g_an_log_scale, i, f32) + ldv(g_lu_log_s, i, f32);
        ws[OFF_LDB] = ldb;
    }
}

// ---------------- main kernel: table-driven, no MFMA / LDS / barriers --------
__global__ __launch_bounds__(BLOCK, 2) void glow_kernel(
    const void* __restrict__ g_eps,
    const void* __restrict__ g_L_tril,
    const float* __restrict__ ws,
    void* __restrict__ g_out)
{
    const bool f32 = (((const float*)g_L_tril)[1] == 0.0f);
    const floatx4* tab = (const floatx4*)(ws + OFF_TAB);

    const int s0 = (blockIdx.x * BLOCK + threadIdx.x) * SPT;

    float z0[SPT], z1[SPT], z2[SPT], ld[SPT];
    {
        const float l00 = ws[OFF_LC + 0], l10 = ws[OFF_LC + 3], l11 = ws[OFF_LC + 4];
        const float l20 = ws[OFF_LC + 6], l21 = ws[OFF_LC + 7], l22 = ws[OFF_LC + 8];
        const float m0 = ws[OFF_MEAN], m1 = ws[OFF_MEAN + 1], m2 = ws[OFF_MEAN + 2];
#pragma unroll
        for (int s = 0; s < SPT; ++s) {
            int g = s0 + s;
            float e0 = ldv(g_eps, g * 3 + 0, f32);
            float e1 = ldv(g_eps, g * 3 + 1, f32);
            float e2 = ldv(g_eps, g * 3 + 2, f32);
            z0[s] = m0 + l00 * e0;
            z1[s] = m1 + l10 * e0 + l11 * e1;
            z2[s] = m2 + l20 * e0 + l21 * e1 + l22 * e2;
            ld[s] = 0.f;
        }
    }

#pragma unroll 1
    for (int f = 0; f < NUM_FLOWS; ++f) {
        const floatx4* cp = (const floatx4*)&ws[OFF_CONST + f * 16];
        floatx4 c0 = cp[0], c1 = cp[1], c2 = cp[2], c3 = cp[3];

        // affine + table index for both samples first (gets all 4 gathers in flight)
        int   ii[SPT];
        float fr[SPT];
#pragma unroll
        for (int s = 0; s < SPT; ++s) {
            float t0 = c2[1] * (z0[s] + c3[0]);
            float t1 = c2[2] * (z1[s] + c3[1]);
            float t2 = c2[3] * (z2[s] + c3[2]);
            z0[s] = c0[0] * t0 + c0[1] * t1 + c0[2] * t2;
            z1[s] = c0[3] * t0 + c1[0] * t1 + c1[1] * t2;
            z2[s] = c1[2] * t0 + c1[3] * t1 + c2[0] * t2;
            float t = (z0[s] - TAB_LO) * TAB_SCALE;
            t = fminf(fmaxf(t, 0.0f), (float)(TABN - 1) - 0.001f);
            int i = (int)t;
            ii[s] = i;
            fr[s] = t - (float)i;
        }
        floatx4 ea[SPT], eb[SPT];
#pragma unroll
        for (int s = 0; s < SPT; ++s) {
            ea[s] = tab[f * TABN + ii[s]];
            eb[s] = tab[f * TABN + ii[s] + 1];
        }
#pragma unroll
        for (int s = 0; s < SPT; ++s) {
            float sh0 = fmaf(fr[s], eb[s][0] - ea[s][0], ea[s][0]);
            float sh1 = fmaf(fr[s], eb[s][1] - ea[s][1], ea[s][1]);
            float ls0 = fmaf(fr[s], eb[s][2] - ea[s][2], ea[s][2]);
            float ls1 = fmaf(fr[s], eb[s][3] - ea[s][3], ea[s][3]);
            z1[s] = fmaf(z1[s], __expf(ls0), sh0);
            z2[s] = fmaf(z2[s], __expf(ls1), sh1);
            ld[s] += ls0 + ls1;
        }
    }

    const float ldBase = ws[OFF_LDB];
#pragma unroll
    for (int s = 0; s < SPT; ++s) {
        int g = s0 + s;
        stv(g_out, g * 3 + 0, z0[s], f32);
        stv(g_out, g * 3 + 1, __expf(z1[s]), f32);
        stv(g_out, g * 3 + 2, __expf(z2[s]), f32);
        stv(g_out, 3 * N_SAMPLES + g, ld[s] + ldBase + z1[s] + z2[s], f32);
    }
}

extern "C" void kernel_launch(void* const* d_in, const int* in_sizes, int n_in,
                              void* d_out, int out_size, void* d_ws, size_t ws_size,
                              hipStream_t stream) {
    prep_kernel<<<dim3(129), dim3(BLOCK), 0, stream>>>(
        d_in[1], d_in[2], d_in[3], d_in[4], d_in[5], d_in[6], d_in[7],
        d_in[8], d_in[9], d_in[10], d_in[11], d_in[12], d_in[13], d_in[14], d_in[15],
        (float*)d_ws);
    glow_kernel<<<dim3(NBLOCKS), dim3(BLOCK), 0, stream>>>(
        d_in[0], d_in[1], (const float*)d_ws, d_out);
}